// Round 10
// baseline (2200.951 us; speedup 1.0000x reference)
//
#include <hip/hip_runtime.h>
#include <hip/hip_cooperative_groups.h>
#include <math.h>
#include <stdint.h>

namespace cg = cooperative_groups;

#define B_ 32
#define C_ 32
#define H_ 16
#define V_ 8192
#define HW_ 256
#define NELEM (B_*C_*H_*H_)   // 262144
#define TBYTES 6208           // per 16-code tile: 3*2048 frag planes + 64 e2sq
#define ZPL 262144            // zb plane stride (elements)

typedef short bf16x8 __attribute__((ext_vector_type(8)));
typedef unsigned short u16x8 __attribute__((ext_vector_type(8)));
typedef float f32x4 __attribute__((ext_vector_type(4)));
typedef unsigned long long ull;

__device__ __forceinline__ unsigned int fkey(float f) {
    unsigned int u = __float_as_uint(f);
    return (u & 0x80000000u) ? ~u : (u | 0x80000000u);
}
__device__ __forceinline__ unsigned short f2bf(float x) {
    unsigned int u = __float_as_uint(x);
    unsigned int r = u + 0x7fffu + ((u >> 16) & 1u);
    return (unsigned short)(r >> 16);
}
__device__ __forceinline__ float bf2f(unsigned short h) {
    return __uint_as_float(((unsigned int)h) << 16);
}

__device__ __forceinline__ void cubic_taps(int i, int pn, float* wt, int* col) {
    double src = ((double)i + 0.5) * ((double)pn / 16.0) - 0.5;
    double fl = floor(src);
    const double A = -0.75;
    #pragma unroll
    for (int k = 0; k < 4; ++k) {
        double j = fl - 1.0 + (double)k;
        double d = fabs(src - j);
        double w;
        if (d <= 1.0)      w = ((A+2.0)*d - (A+3.0))*d*d + 1.0;
        else if (d < 2.0)  w = ((A*d - 5.0*A)*d + 8.0*A)*d - 4.0*A;
        else               w = 0.0;
        wt[k] = (float)w;
        int jj = (int)j;
        col[k] = jj < 0 ? 0 : (jj > pn-1 ? pn-1 : jj);
    }
}

__device__ __forceinline__ void qstep(
    const bf16x8 a0, const bf16x8 a1, const bf16x8 a2, const f32x4 e2v,
    const bf16x8* Bf, int cbase, float& dmin, int& imin)
{
    f32x4 acc = e2v;
    acc = __builtin_amdgcn_mfma_f32_16x16x32_bf16(a0, Bf[0], acc, 0, 0, 0);
    acc = __builtin_amdgcn_mfma_f32_16x16x32_bf16(a1, Bf[0], acc, 0, 0, 0);
    acc = __builtin_amdgcn_mfma_f32_16x16x32_bf16(a0, Bf[1], acc, 0, 0, 0);
    acc = __builtin_amdgcn_mfma_f32_16x16x32_bf16(a2, Bf[0], acc, 0, 0, 0);
    acc = __builtin_amdgcn_mfma_f32_16x16x32_bf16(a1, Bf[1], acc, 0, 0, 0);
    acc = __builtin_amdgcn_mfma_f32_16x16x32_bf16(a0, Bf[2], acc, 0, 0, 0);
    float mt = fminf(fminf(acc.x, acc.y), fminf(acc.z, acc.w));
    if (mt < dmin) {
        dmin = mt;
        imin = cbase + ((acc.x==mt) ? 0 : (acc.y==mt) ? 1 : (acc.z==mt) ? 2 : 3);
    }
}

struct MegaParams {
    const float* f; const float* emb; const float* cw; const float* cb;
    float* out;
    ull* best0; ull* best1;
    float* f_rest; float* f_hat;
    unsigned short* zb; char* blob;
    float* lossAcc; float* h_up;
    int phi_idx[10];
};

// ---- phase bodies (verbatim from the round-9 passing kernels) ----

__device__ void vq_block(const char* __restrict__ blob,
                         const unsigned short* __restrict__ zb,
                         ull* __restrict__ best, int N, int lvs,
                         int wb, int tid)
{
    int lane = tid & 63, w = tid >> 6;
    int qtiles_total = N >> 4;
    int qb = wb >> lvs;
    int vc = wb & ((1 << lvs) - 1);
    int tiles = 512 >> lvs;
    int t0 = vc * tiles;
    int qt0 = qb*16 + w*4;
    int qr = lane & 15, kq = lane >> 4;

    bf16x8 Bf0[3], Bf1[3], Bf2[3], Bf3[3];
    int qv0, qv1, qv2, qv3;
    {
        int qtj; size_t o;
        qtj = qt0 + 0; qv0 = (qtj < qtiles_total);
        o = (size_t)((qv0 ? qtj : 0)*16 + qr)*C_ + kq*8;
        Bf0[0] = *(const bf16x8*)(zb + o);
        Bf0[1] = *(const bf16x8*)(zb + o + ZPL);
        Bf0[2] = *(const bf16x8*)(zb + o + 2*ZPL);
        qtj = qt0 + 1; qv1 = (qtj < qtiles_total);
        o = (size_t)((qv1 ? qtj : 0)*16 + qr)*C_ + kq*8;
        Bf1[0] = *(const bf16x8*)(zb + o);
        Bf1[1] = *(const bf16x8*)(zb + o + ZPL);
        Bf1[2] = *(const bf16x8*)(zb + o + 2*ZPL);
        qtj = qt0 + 2; qv2 = (qtj < qtiles_total);
        o = (size_t)((qv2 ? qtj : 0)*16 + qr)*C_ + kq*8;
        Bf2[0] = *(const bf16x8*)(zb + o);
        Bf2[1] = *(const bf16x8*)(zb + o + ZPL);
        Bf2[2] = *(const bf16x8*)(zb + o + 2*ZPL);
        qtj = qt0 + 3; qv3 = (qtj < qtiles_total);
        o = (size_t)((qv3 ? qtj : 0)*16 + qr)*C_ + kq*8;
        Bf3[0] = *(const bf16x8*)(zb + o);
        Bf3[1] = *(const bf16x8*)(zb + o + ZPL);
        Bf3[2] = *(const bf16x8*)(zb + o + 2*ZPL);
    }

    float dmin[4]; int imin[4];
    #pragma unroll
    for (int j = 0; j < 4; ++j) { dmin[j] = __builtin_inff(); imin[j] = 0; }

    const char* tb = blob + (size_t)t0*TBYTES;
    bf16x8 Xa0, Xa1, Xa2; f32x4 Xe;
    bf16x8 Ya0, Ya1, Ya2; f32x4 Ye;
    Xa0 = *(const bf16x8*)(tb +        lane*16);
    Xa1 = *(const bf16x8*)(tb + 2048 + lane*16);
    Xa2 = *(const bf16x8*)(tb + 4096 + lane*16);
    Xe  = *(const f32x4*)(tb + 6144 + kq*16);

    for (int tt = 0; tt < tiles; tt += 2) {
        const char* nb = tb + TBYTES;
        Ya0 = *(const bf16x8*)(nb +        lane*16);
        Ya1 = *(const bf16x8*)(nb + 2048 + lane*16);
        Ya2 = *(const bf16x8*)(nb + 4096 + lane*16);
        Ye  = *(const f32x4*)(nb + 6144 + kq*16);
        {
            int cbase = (t0 + tt)*16 + kq*4;
            qstep(Xa0, Xa1, Xa2, Xe, Bf0, cbase, dmin[0], imin[0]);
            qstep(Xa0, Xa1, Xa2, Xe, Bf1, cbase, dmin[1], imin[1]);
            qstep(Xa0, Xa1, Xa2, Xe, Bf2, cbase, dmin[2], imin[2]);
            qstep(Xa0, Xa1, Xa2, Xe, Bf3, cbase, dmin[3], imin[3]);
        }
        const char* nb2 = (tt + 2 < tiles) ? tb + 2*TBYTES : tb;
        Xa0 = *(const bf16x8*)(nb2 +        lane*16);
        Xa1 = *(const bf16x8*)(nb2 + 2048 + lane*16);
        Xa2 = *(const bf16x8*)(nb2 + 4096 + lane*16);
        Xe  = *(const f32x4*)(nb2 + 6144 + kq*16);
        {
            int cbase = (t0 + tt + 1)*16 + kq*4;
            qstep(Ya0, Ya1, Ya2, Ye, Bf0, cbase, dmin[0], imin[0]);
            qstep(Ya0, Ya1, Ya2, Ye, Bf1, cbase, dmin[1], imin[1]);
            qstep(Ya0, Ya1, Ya2, Ye, Bf2, cbase, dmin[2], imin[2]);
            qstep(Ya0, Ya1, Ya2, Ye, Bf3, cbase, dmin[3], imin[3]);
        }
        tb += 2*TBYTES;
    }

    int qvv[4] = {qv0, qv1, qv2, qv3};
    #pragma unroll
    for (int j = 0; j < 4; ++j) {
        ull key = ((ull)fkey(dmin[j]) << 32) | (unsigned int)imin[j];
        ull o1 = __shfl_xor(key, 16); key = o1 < key ? o1 : key;
        ull o2 = __shfl_xor(key, 32); key = o2 < key ? o2 : key;
        if (kq == 0 && qvv[j]) {
            int q = (qt0 + j)*16 + qr;
            atomicMin(best + q, key);
        }
    }
}

__device__ void up_item(const ull* __restrict__ best,
                        const float* __restrict__ emb,
                        float* __restrict__ h_up, int pn, int i)
{
    int c  = i & 31;
    int px = (i >> 5) & 255;
    int bi = i >> 13;
    int h = px >> 4, w = px & 15;
    float wh[4]; int th[4];
    float wwt[4]; int tw[4];
    cubic_taps(h, pn, wh, th);
    cubic_taps(w, pn, wwt, tw);
    const ull* bptr = best + bi*pn*pn;
    float acc = 0.f;
    #pragma unroll
    for (int ii = 0; ii < 4; ++ii) {
        if (wh[ii] == 0.f) continue;
        #pragma unroll
        for (int j = 0; j < 4; ++j) {
            float wt = wh[ii]*wwt[j];
            if (wt == 0.f) continue;
            unsigned int idx = (unsigned int)(bptr[th[ii]*pn + tw[j]] & 0xffffffffull);
            acc = fmaf(wt, emb[(size_t)idx*C_ + c], acc);
        }
    }
    h_up[(size_t)bi*8192 + px*32 + c] = acc;
}

__device__ void conv_block(const float* __restrict__ h_up,
                           const float* __restrict__ cw, const float* __restrict__ cb,
                           const float* __restrict__ forig,
                           float* __restrict__ f_hat, float* __restrict__ f_rest,
                           float* __restrict__ lossAcc,
                           int pn2, unsigned short* __restrict__ zb,
                           ull* __restrict__ bestN,
                           int wb, int tid,
                           float (*hup)[33], float* frs, float* red)
{
    int bi = wb >> 5;
    int co = wb & 31;
    int h = tid >> 4, w = tid & 15;

    const float4* src = (const float4*)(h_up + (size_t)bi*8192);
    #pragma unroll
    for (int cc = 0; cc < 8; ++cc) {
        int f4 = cc*256 + tid;
        float4 v = src[f4];
        int px2 = f4 >> 3, c0 = (f4 & 7)*4;
        float* hp = &hup[px2][c0];
        hp[0] = v.x; hp[1] = v.y; hp[2] = v.z; hp[3] = v.w;
    }
    __syncthreads();

    float o = cb[co];
    const float* wbase = cw + (size_t)co*C_*9;
    for (int ci = 0; ci < 32; ++ci) {
        const float* wr = wbase + ci*9;
        float s = 0.f;
        #pragma unroll
        for (int dh = 0; dh < 3; ++dh) {
            int hh = h + dh - 1;
            #pragma unroll
            for (int dw = 0; dw < 3; ++dw) {
                int ww2 = w + dw - 1;
                bool ok = (hh >= 0) & (hh < 16) & (ww2 >= 0) & (ww2 < 16);
                float hv = ok ? hup[((hh & 15) << 4) | (ww2 & 15)][ci] : 0.f;
                s = fmaf(hv, wr[dh*3+dw], s);
            }
        }
        o += s;
    }

    float hv0 = hup[tid][co];
    float outv = 0.5f*hv0 + 0.5f*o;
    size_t off = ((size_t)(bi*C_ + co))*HW_ + tid;
    float fh = f_hat[off] + outv;
    f_hat[off] = fh;
    float fr = f_rest[off] - outv;
    f_rest[off] = fr;
    float df = fh - forig[off];
    float sq = df*df;
    frs[tid] = fr;
    #pragma unroll
    for (int o2 = 32; o2 > 0; o2 >>= 1) sq += __shfl_down(sq, o2, 64);
    if ((tid & 63) == 0) red[tid >> 6] = sq;
    __syncthreads();
    if (tid == 0) atomicAdd(lossAcc, (red[0]+red[1])+(red[2]+red[3]));

    if (pn2 > 0 && h < pn2 && w < pn2) {
        int hs = (h*H_)/pn2,  he2 = ((h+1)*H_ + pn2-1)/pn2;
        int ws2 = (w*H_)/pn2, we2 = ((w+1)*H_ + pn2-1)/pn2;
        float inv = (1.f/(float)(he2-hs)) * (1.f/(float)(we2-ws2));
        int n = bi*pn2*pn2 + h*pn2 + w;
        float s = 0.f;
        for (int hh = hs; hh < he2; ++hh)
            for (int ww = ws2; ww < we2; ++ww)
                s += frs[(hh << 4) | ww];
        float x = s * inv;
        unsigned short b0 = f2bf(x);  float r1 = x - bf2f(b0);
        unsigned short b1 = f2bf(r1); float r2 = r1 - bf2f(b1);
        unsigned short b2 = f2bf(r2);
        size_t oo = (size_t)n*C_ + co;
        zb[oo] = b0; zb[oo + ZPL] = b1; zb[oo + 2*ZPL] = b2;
        if (co == 0) bestN[n] = ~0ull;
    }
    __syncthreads();   // safe reuse of hup/frs on next wb iteration
}

// ---- the single persistent cooperative kernel ----
__global__ void __launch_bounds__(256, 4) k_mega(MegaParams P)
{
    cg::grid_group gg = cg::this_grid();
    __shared__ float hup[256][33];
    __shared__ float frs[256];
    __shared__ float red[4];
    const int tid  = threadIdx.x;
    const int blk  = blockIdx.x;
    const int nblk = gridDim.x;

    // ---- P0: init f_rest/f_hat, build blob, pool scale 0, zero loss ----
    for (int i = blk*256 + tid; i < NELEM; i += nblk*256) {
        float v = P.f[i]; P.f_rest[i] = v; P.f_hat[i] = 0.f;
        if (i < 512*64) {
            int t = i >> 6, l = i & 63;
            int row = t*16 + (l & 15);
            int k0 = (l >> 4) * 8;
            const float* er = P.emb + row*C_ + k0;
            u16x8 h0, h1, h2;
            #pragma unroll
            for (int j = 0; j < 8; ++j) {
                float x = -2.f * er[j];
                unsigned short b0 = f2bf(x);  float r1 = x - bf2f(b0);
                unsigned short b1 = f2bf(r1); float r2 = r1 - bf2f(b1);
                unsigned short b2 = f2bf(r2);
                h0[j] = b0; h1[j] = b1; h2[j] = b2;
            }
            char* tb = P.blob + (size_t)t*TBYTES;
            *(u16x8*)(tb +        l*16) = h0;
            *(u16x8*)(tb + 2048 + l*16) = h1;
            *(u16x8*)(tb + 4096 + l*16) = h2;
            if ((l >> 4) == 0) {
                const float4* e4 = (const float4*)(P.emb + row*C_);
                float s = 0.f;
                #pragma unroll
                for (int cc = 0; cc < 8; ++cc) {
                    float4 ev = e4[cc];
                    s += ev.x*ev.x + ev.y*ev.y + ev.z*ev.z + ev.w*ev.w;
                }
                *(float*)(tb + 6144 + (l & 15)*4) = s;
            }
        }
        if (i < 1024) {          // pool scale 0 (pn=1): reads input f directly
            int c = i & 31, n = i >> 5;
            if (c == 0) P.best0[n] = ~0ull;
            const float* base = P.f + ((size_t)(n*C_ + c))*HW_;
            float s = 0.f;
            for (int hh = 0; hh < 16; ++hh)
                for (int ww = 0; ww < 16; ++ww)
                    s += base[hh*H_ + ww];
            float x = s * ((1.f/16.f)*(1.f/16.f));
            unsigned short b0 = f2bf(x);  float r1 = x - bf2f(b0);
            unsigned short b1 = f2bf(r1); float r2 = r1 - bf2f(b1);
            unsigned short b2 = f2bf(r2);
            size_t o = (size_t)n*C_ + c;
            P.zb[o] = b0; P.zb[o + ZPL] = b1; P.zb[o + 2*ZPL] = b2;
        }
        if (i == 0) P.lossAcc[0] = 0.f;
    }
    gg.sync();

    static const int pns[10]  = {1,2,3,4,5,6,8,10,13,16};
    static const int lvss[10] = {6,6,6,6,6,6,6,5,5,4};

    for (int si = 0; si < 10; ++si) {
        const int pn = pns[si];
        const int N = B_*pn*pn;
        const int lvs = lvss[si];
        const int qtiles_total = N >> 4;
        const int qblocks = (qtiles_total + 15) >> 4;
        const int vqb = qblocks << lvs;
        ull* bcur  = (si & 1) ? P.best1 : P.best0;
        ull* bnext = (si & 1) ? P.best0 : P.best1;

        for (int wb = blk; wb < vqb; wb += nblk)
            vq_block(P.blob, P.zb, bcur, N, lvs, wb, tid);
        gg.sync();

        for (int i = blk*256 + tid; i < NELEM; i += nblk*256)
            up_item(bcur, P.emb, P.h_up, pn, i);
        gg.sync();

        const float* cwp = P.cw + (size_t)P.phi_idx[si]*C_*C_*9;
        const float* cbp = P.cb + (size_t)P.phi_idx[si]*C_;
        const int pn2 = (si < 9) ? pns[si+1] : 0;
        for (int wb = blk; wb < B_*32; wb += nblk)
            conv_block(P.h_up, cwp, cbp, P.f, P.f_hat, P.f_rest, P.lossAcc,
                       pn2, P.zb, bnext, wb, tid, hup, frs, red);
        gg.sync();
    }

    for (int i = blk*256 + tid; i < NELEM; i += nblk*256)
        P.out[i] = P.f_hat[i];
    if (blk == 0 && tid == 0)
        P.out[NELEM] = P.lossAcc[0] * 1.25f / ((float)NELEM * 10.f);
}

extern "C" void kernel_launch(void* const* d_in, const int* in_sizes, int n_in,
                              void* d_out, int out_size, void* d_ws, size_t ws_size,
                              hipStream_t stream)
{
    char* ws = (char*)d_ws;
    MegaParams P;
    P.f   = (const float*)d_in[0];
    P.emb = (const float*)d_in[1];
    P.cw  = (const float*)d_in[2];
    P.cb  = (const float*)d_in[3];
    P.out = (float*)d_out;
    P.best0  = (ull*)ws;                                  // 64 KB
    P.best1  = (ull*)(ws + 65536);                        // 64 KB
    P.f_rest = (float*)(ws + 131072);                     // 1 MB
    P.f_hat  = (float*)(ws + 131072 + 1048576);           // 1 MB
    P.zb     = (unsigned short*)(ws + 2228224);           // 1.5 MB
    P.blob   = ws + 3801088;                              // 512*6208 B
    P.lossAcc= (float*)(ws + 6979584);
    P.h_up   = (float*)(ws + 7340032);                    // 1 MB

    // Replicate PHI_IDX with numpy-linspace double semantics (no FP contraction)
    volatile double a   = 1.0/3.0/4.0;
    volatile double bb  = 1.0 - a;
    volatile double stp = (bb - a) / 3.0;
    double ticks[4];
    for (int i = 0; i < 4; ++i) { volatile double m = (double)i * stp; ticks[i] = m + a; }
    ticks[3] = bb;
    for (int si = 0; si < 10; ++si) {
        volatile double x = (double)si / 9.0;
        int bi = 0; double bd = fabs(ticks[0] - x);
        for (int k = 1; k < 4; ++k) {
            double d = fabs(ticks[k] - x);
            if (d < bd) { bd = d; bi = k; }
        }
        P.phi_idx[si] = bi;
    }

    int maxB = 0;
    hipOccupancyMaxActiveBlocksPerMultiprocessor(&maxB, (const void*)k_mega, 256, 0);
    if (maxB < 1) maxB = 1;
    int G = maxB * 256;          // 256 CUs on MI355X
    if (G > 1024) G = 1024;

    void* args[] = { (void*)&P };
    hipLaunchCooperativeKernel((const void*)k_mega, dim3(G), dim3(256),
                               args, 0, stream);
}

// Round 12
// 868.545 us; speedup vs baseline: 2.5341x; 2.5341x over previous
//
#include <hip/hip_runtime.h>
#include <math.h>
#include <stdint.h>

#define B_ 32
#define C_ 32
#define H_ 16
#define V_ 8192
#define NELEM (B_*C_*H_*H_)   // 262144
#define TBYTES 6208           // per 16-code tile: 3*2048 A-frag planes + 64 e2sq
#define ZPL 262144            // zb plane stride (elements)

typedef short bf16x8 __attribute__((ext_vector_type(8)));
typedef unsigned short u16x8 __attribute__((ext_vector_type(8)));
typedef float f32x4 __attribute__((ext_vector_type(4)));
typedef unsigned long long ull;

__device__ __forceinline__ unsigned int fkey(float f) {
    unsigned int u = __float_as_uint(f);
    return (u & 0x80000000u) ? ~u : (u | 0x80000000u);
}
__device__ __forceinline__ unsigned short f2bf(float x) {
    unsigned int u = __float_as_uint(x);
    unsigned int r = u + 0x7fffu + ((u >> 16) & 1u);
    return (unsigned short)(r >> 16);
}
__device__ __forceinline__ float bf2f(unsigned short h) {
    return __uint_as_float(((unsigned int)h) << 16);
}

// build E-fragment blob (A-frag order, -2E bf16x3 + e2sq); zero ctr/lossAcc
__global__ void __launch_bounds__(256) k_init(
    const float* __restrict__ emb, char* __restrict__ blob,
    float* __restrict__ lossAcc, unsigned int* __restrict__ ctr)
{
    int i = blockIdx.x*256 + threadIdx.x;   // 32768 = 512 tiles * 64
    int t = i >> 6, l = i & 63;
    int row = t*16 + (l & 15);
    int k0 = (l >> 4) * 8;
    const float* er = emb + row*C_ + k0;
    u16x8 h0, h1, h2;
    #pragma unroll
    for (int j = 0; j < 8; ++j) {
        float x = -2.f * er[j];
        unsigned short b0 = f2bf(x);  float r1 = x - bf2f(b0);
        unsigned short b1 = f2bf(r1); float r2 = r1 - bf2f(b1);
        unsigned short b2 = f2bf(r2);
        h0[j] = b0; h1[j] = b1; h2[j] = b2;
    }
    char* tb = blob + (size_t)t*TBYTES;
    *(u16x8*)(tb +        l*16) = h0;
    *(u16x8*)(tb + 2048 + l*16) = h1;
    *(u16x8*)(tb + 4096 + l*16) = h2;
    if ((l >> 4) == 0) {
        const float4* e4 = (const float4*)(emb + row*C_);
        float s = 0.f;
        #pragma unroll
        for (int cc = 0; cc < 8; ++cc) {
            float4 ev = e4[cc];
            s += ev.x*ev.x + ev.y*ev.y + ev.z*ev.z + ev.w*ev.w;
        }
        *(float*)(tb + 6144 + (l & 15)*4) = s;
    }
    if (i < 1024) ctr[i] = 0;
    if (i == 0) lossAcc[0] = 0.f;
}

__device__ __forceinline__ void qstep(
    const bf16x8 a0, const bf16x8 a1, const bf16x8 a2, const f32x4 e2v,
    const bf16x8* Bf, int cbase, float& dmin, int& imin)
{
    f32x4 acc = e2v;
    acc = __builtin_amdgcn_mfma_f32_16x16x32_bf16(a0, Bf[0], acc, 0, 0, 0);
    acc = __builtin_amdgcn_mfma_f32_16x16x32_bf16(a1, Bf[0], acc, 0, 0, 0);
    acc = __builtin_amdgcn_mfma_f32_16x16x32_bf16(a0, Bf[1], acc, 0, 0, 0);
    acc = __builtin_amdgcn_mfma_f32_16x16x32_bf16(a2, Bf[0], acc, 0, 0, 0);
    acc = __builtin_amdgcn_mfma_f32_16x16x32_bf16(a1, Bf[1], acc, 0, 0, 0);
    acc = __builtin_amdgcn_mfma_f32_16x16x32_bf16(a0, Bf[2], acc, 0, 0, 0);
    float mt = fminf(fminf(acc.x, acc.y), fminf(acc.z, acc.w));
    if (mt < dmin) {
        dmin = mt;
        imin = cbase + ((acc.x==mt) ? 0 : (acc.y==mt) ? 1 : (acc.z==mt) ? 2 : 3);
    }
}

__device__ __forceinline__ void cubic_taps(int i, int pn, float* wt, int* col) {
    double src = ((double)i + 0.5) * ((double)pn / 16.0) - 0.5;
    double fl = floor(src);
    const double A = -0.75;
    #pragma unroll
    for (int k = 0; k < 4; ++k) {
        double j = fl - 1.0 + (double)k;
        double d = fabs(src - j);
        double w;
        if (d <= 1.0)      w = ((A+2.0)*d - (A+3.0))*d*d + 1.0;
        else if (d < 2.0)  w = ((A*d - 5.0*A)*d + 8.0*A)*d - 4.0*A;
        else               w = 0.0;
        wt[k] = (float)w;
        int jj = (int)j;
        col[k] = jj < 0 ? 0 : (jj > pn-1 ? pn-1 : jj);
    }
}

// per-image 8-block barrier; one dedicated counter per (image, instance)
__device__ __forceinline__ void img_barrier(unsigned int* c) {
    __syncthreads();
    if (threadIdx.x == 0) {
        __hip_atomic_fetch_add(c, 1u, __ATOMIC_RELEASE, __HIP_MEMORY_SCOPE_AGENT);
        while (__hip_atomic_load(c, __ATOMIC_ACQUIRE, __HIP_MEMORY_SCOPE_AGENT) < 8u)
            __builtin_amdgcn_s_sleep(1);
    }
    __syncthreads();
}

// pool this block's 4 channels of frL -> global zb bf16x3 planes
__device__ __forceinline__ void pool_to_zb(
    const float* frL, unsigned short* zb, int bi, int pn2, int co0, int tid)
{
    int pp2 = pn2*pn2;
    int items = pp2*4;
    for (int it = tid; it < items; it += 512) {
        int k = it & 3, cell = it >> 2;
        int h2 = cell / pn2, w2 = cell - h2*pn2;
        int hs = (h2*H_)/pn2,  he = ((h2+1)*H_ + pn2-1)/pn2;
        int ws = (w2*H_)/pn2,  we = ((w2+1)*H_ + pn2-1)/pn2;
        float s = 0.f;
        for (int hh = hs; hh < he; ++hh)
            for (int ww = ws; ww < we; ++ww)
                s += frL[(hh*H_+ww)*4 + k];
        float inv = (1.f/(float)(he-hs)) * (1.f/(float)(we-ws));
        float x = s * inv;
        unsigned short b0 = f2bf(x);  float r1 = x - bf2f(b0);
        unsigned short b1 = f2bf(r1); float r2 = r1 - bf2f(b1);
        unsigned short b2 = f2bf(r2);
        size_t o = (size_t)(bi*pp2 + cell)*C_ + co0 + k;
        zb[o] = b0; zb[o + ZPL] = b1; zb[o + 2*ZPL] = b2;
    }
}

struct MegaP {
    const float *f, *emb, *cw, *cb;
    const char* blob;
    unsigned short* zb;
    ull* best0; ull* best1;
    unsigned int* ctr;
    float* lossAcc; float* out;
    int phi[10];
};

// 256 blocks x 512 thr: block = (image bi, shard j). Shard owns V-slice j
// (64 code tiles) and channels 4j..4j+3 (f_rest/f_hat in LDS, all scales).
__global__ void __launch_bounds__(512, 2) k_mega(MegaP P)
{
    __shared__ float huL[256*33];     // full h_up, all 32 channels
    __shared__ float frL[256*4];      // f_rest shard (4 channels)
    __shared__ float fhL[256*4];      // f_hat shard
    __shared__ float wtT[64];
    __shared__ int   colT[64];
    __shared__ float red[8];

    const int tid = threadIdx.x;
    const int bi = blockIdx.x >> 3;
    const int j  = blockIdx.x & 7;
    const int co0 = j*4;
    const int lane = tid & 63, wid = tid >> 6;
    const int qr = lane & 15, kq = lane >> 4;
    const float* fimg = P.f + (size_t)bi*8192;

    // prologue: load shard, init best0, pool scale-0 z
    for (int it = tid; it < 1024; it += 512) {
        int k = it >> 8, px = it & 255;
        frL[px*4 + k] = fimg[(co0+k)*256 + px];
        fhL[px*4 + k] = 0.f;
    }
    if (tid < 256) P.best0[bi*256 + tid] = ~0ull;
    __syncthreads();
    pool_to_zb(frL, P.zb, bi, 1, co0, tid);
    img_barrier(&P.ctr[bi*32 + 0]);

    static const int pns[10] = {1,2,3,4,5,6,8,10,13,16};

    for (int si = 0; si < 10; ++si) {
        const int pn = pns[si], pp = pn*pn;
        const int qtiles = (pp + 15) >> 4;
        const int ngroups = (qtiles + 3) >> 2;
        ull* bcur  = (si & 1) ? P.best1 : P.best0;
        ull* bnext = (si & 1) ? P.best0 : P.best1;

        // ---- VQ: this shard's 64 code tiles (8/wave), all query tiles ----
        {
            const int t0 = j*64 + wid*8;
            const unsigned short* zq = P.zb + (size_t)bi*pp*C_;
            for (int g = 0; g < ngroups; ++g) {
                bf16x8 B0[3], B1[3], B2[3], B3[3];
                int v0, v1, v2, v3;
                {
                    int row; size_t o;
                    row = (g*4+0)*16 + qr; v0 = (row < pp);
                    o = (size_t)(v0 ? row : 0)*C_ + kq*8;
                    B0[0] = *(const bf16x8*)(zq + o);
                    B0[1] = *(const bf16x8*)(zq + o + ZPL);
                    B0[2] = *(const bf16x8*)(zq + o + 2*ZPL);
                    row = (g*4+1)*16 + qr; v1 = (row < pp);
                    o = (size_t)(v1 ? row : 0)*C_ + kq*8;
                    B1[0] = *(const bf16x8*)(zq + o);
                    B1[1] = *(const bf16x8*)(zq + o + ZPL);
                    B1[2] = *(const bf16x8*)(zq + o + 2*ZPL);
                    row = (g*4+2)*16 + qr; v2 = (row < pp);
                    o = (size_t)(v2 ? row : 0)*C_ + kq*8;
                    B2[0] = *(const bf16x8*)(zq + o);
                    B2[1] = *(const bf16x8*)(zq + o + ZPL);
                    B2[2] = *(const bf16x8*)(zq + o + 2*ZPL);
                    row = (g*4+3)*16 + qr; v3 = (row < pp);
                    o = (size_t)(v3 ? row : 0)*C_ + kq*8;
                    B3[0] = *(const bf16x8*)(zq + o);
                    B3[1] = *(const bf16x8*)(zq + o + ZPL);
                    B3[2] = *(const bf16x8*)(zq + o + 2*ZPL);
                }
                float dmin[4]; int imin[4];
                #pragma unroll
                for (int q = 0; q < 4; ++q) { dmin[q] = __builtin_inff(); imin[q] = 0; }

                const char* tb = P.blob + (size_t)t0*TBYTES;
                bf16x8 Xa0, Xa1, Xa2; f32x4 Xe;
                bf16x8 Ya0, Ya1, Ya2; f32x4 Ye;
                Xa0 = *(const bf16x8*)(tb +        lane*16);
                Xa1 = *(const bf16x8*)(tb + 2048 + lane*16);
                Xa2 = *(const bf16x8*)(tb + 4096 + lane*16);
                Xe  = *(const f32x4*)(tb + 6144 + kq*16);

                for (int tt = 0; tt < 8; tt += 2) {
                    const char* nb = tb + TBYTES;
                    Ya0 = *(const bf16x8*)(nb +        lane*16);
                    Ya1 = *(const bf16x8*)(nb + 2048 + lane*16);
                    Ya2 = *(const bf16x8*)(nb + 4096 + lane*16);
                    Ye  = *(const f32x4*)(nb + 6144 + kq*16);
                    {
                        int cbase = (t0 + tt)*16 + kq*4;
                        qstep(Xa0, Xa1, Xa2, Xe, B0, cbase, dmin[0], imin[0]);
                        qstep(Xa0, Xa1, Xa2, Xe, B1, cbase, dmin[1], imin[1]);
                        qstep(Xa0, Xa1, Xa2, Xe, B2, cbase, dmin[2], imin[2]);
                        qstep(Xa0, Xa1, Xa2, Xe, B3, cbase, dmin[3], imin[3]);
                    }
                    const char* nb2 = (tt + 2 < 8) ? tb + 2*TBYTES : tb;
                    Xa0 = *(const bf16x8*)(nb2 +        lane*16);
                    Xa1 = *(const bf16x8*)(nb2 + 2048 + lane*16);
                    Xa2 = *(const bf16x8*)(nb2 + 4096 + lane*16);
                    Xe  = *(const f32x4*)(nb2 + 6144 + kq*16);
                    {
                        int cbase = (t0 + tt + 1)*16 + kq*4;
                        qstep(Ya0, Ya1, Ya2, Ye, B0, cbase, dmin[0], imin[0]);
                        qstep(Ya0, Ya1, Ya2, Ye, B1, cbase, dmin[1], imin[1]);
                        qstep(Ya0, Ya1, Ya2, Ye, B2, cbase, dmin[2], imin[2]);
                        qstep(Ya0, Ya1, Ya2, Ye, B3, cbase, dmin[3], imin[3]);
                    }
                    tb += 2*TBYTES;
                }
                int vv[4] = {v0, v1, v2, v3};
                #pragma unroll
                for (int q = 0; q < 4; ++q) {
                    ull key = ((ull)fkey(dmin[q]) << 32) | (unsigned int)imin[q];
                    ull o1 = __shfl_xor(key, 16); key = o1 < key ? o1 : key;
                    ull o2 = __shfl_xor(key, 32); key = o2 < key ? o2 : key;
                    if (kq == 0 && vv[q])
                        atomicMin(&bcur[bi*256 + (g*4+q)*16 + qr], key);
                }
            }
        }
        img_barrier(&P.ctr[bi*32 + 1 + 2*si]);

        if (tid < 16) cubic_taps(tid, pn, &wtT[tid*4], &colT[tid*4]);
        __syncthreads();

        // ---- UP: full h_up (all 32 channels) into LDS ----
        {
            const ull* bptr = bcur + bi*256;
            for (int it = tid; it < 8192; it += 512) {
                int c = it & 31, px = it >> 5;
                int h = px >> 4, w2 = px & 15;
                float acc = 0.f;
                #pragma unroll
                for (int ii = 0; ii < 4; ++ii) {
                    float whv = wtT[h*4+ii];
                    if (whv == 0.f) continue;
                    int th = colT[h*4+ii];
                    #pragma unroll
                    for (int jj = 0; jj < 4; ++jj) {
                        float wt = whv * wtT[w2*4+jj];
                        if (wt == 0.f) continue;
                        unsigned int idx =
                            (unsigned int)(bptr[th*pn + colT[w2*4+jj]] & 0xffffffffull);
                        acc = fmaf(wt, P.emb[(size_t)idx*C_ + c], acc);
                    }
                }
                huL[px*33 + c] = acc;
            }
        }
        __syncthreads();

        // ---- CONV (2 output channels per thread-half) + Phi + updates ----
        {
            int px = tid & 255, half = tid >> 8;
            int h = px >> 4, w2 = px & 15;
            int cA = co0 + half*2;
            const float* cwp = P.cw + (size_t)P.phi[si]*9216;
            const float* cbp = P.cb + (size_t)P.phi[si]*C_;
            float o0 = cbp[cA], o1 = cbp[cA+1];
            for (int ci = 0; ci < 32; ++ci) {
                float hv[9];
                #pragma unroll
                for (int dh = 0; dh < 3; ++dh) {
                    int hh = h + dh - 1;
                    #pragma unroll
                    for (int dw = 0; dw < 3; ++dw) {
                        int ww = w2 + dw - 1;
                        bool ok = (hh >= 0) & (hh < 16) & (ww >= 0) & (ww < 16);
                        int npx = ((hh & 15) << 4) | (ww & 15);
                        hv[dh*3+dw] = ok ? huL[npx*33 + ci] : 0.f;
                    }
                }
                const float* w0 = cwp + (size_t)cA*288 + ci*9;
                const float* w1 = w0 + 288;
                float s0 = 0.f, s1 = 0.f;
                #pragma unroll
                for (int t = 0; t < 9; ++t) {
                    s0 = fmaf(hv[t], w0[t], s0);
                    s1 = fmaf(hv[t], w1[t], s1);
                }
                o0 += s0; o1 += s1;
            }
            float sq = 0.f;
            {
                int co = cA, kk = half*2;
                float hv0 = huL[px*33 + co];
                float outv = 0.5f*hv0 + 0.5f*o0;
                float fh = fhL[px*4 + kk] + outv;
                fhL[px*4 + kk] = fh;
                frL[px*4 + kk] -= outv;
                float df = fh - fimg[co*256 + px];
                sq = fmaf(df, df, sq);
            }
            {
                int co = cA+1, kk = half*2+1;
                float hv0 = huL[px*33 + co];
                float outv = 0.5f*hv0 + 0.5f*o1;
                float fh = fhL[px*4 + kk] + outv;
                fhL[px*4 + kk] = fh;
                frL[px*4 + kk] -= outv;
                float df = fh - fimg[co*256 + px];
                sq = fmaf(df, df, sq);
            }
            #pragma unroll
            for (int o2 = 32; o2 > 0; o2 >>= 1) sq += __shfl_down(sq, o2, 64);
            if (lane == 0) red[wid] = sq;
        }
        __syncthreads();
        if (tid == 0) {
            float s = 0.f;
            #pragma unroll
            for (int r = 0; r < 8; ++r) s += red[r];
            atomicAdd(P.lossAcc, s);
        }

        // ---- POOL next-scale z + reset next best ----
        if (si < 9) pool_to_zb(frL, P.zb, bi, pns[si+1], co0, tid);
        if (tid < 256) bnext[bi*256 + tid] = ~0ull;
        img_barrier(&P.ctr[bi*32 + 2 + 2*si]);
    }

    // epilogue: write this shard's channels of f_hat
    for (int it = tid; it < 1024; it += 512) {
        int k = it >> 8, px = it & 255;
        P.out[(size_t)bi*8192 + (co0+k)*256 + px] = fhL[px*4 + k];
    }
}

__global__ void k_final(const float* __restrict__ lossAcc, float* __restrict__ out)
{
    if (blockIdx.x == 0 && threadIdx.x == 0)
        out[NELEM] = lossAcc[0] * 1.25f / ((float)NELEM * 10.f);
}

extern "C" void kernel_launch(void* const* d_in, const int* in_sizes, int n_in,
                              void* d_out, int out_size, void* d_ws, size_t ws_size,
                              hipStream_t stream)
{
    char* ws = (char*)d_ws;
    MegaP P;
    P.f   = (const float*)d_in[0];
    P.emb = (const float*)d_in[1];
    P.cw  = (const float*)d_in[2];
    P.cb  = (const float*)d_in[3];
    P.blob = ws;                                            // 3,178,496 B
    P.zb   = (unsigned short*)(ws + 3178496);               // 1,572,864 B
    P.best0 = (ull*)(ws + 4751360);                         // 65,536 B
    P.best1 = (ull*)(ws + 4816896);                         // 65,536 B
    P.ctr   = (unsigned int*)(ws + 4882432);                // 4,096 B
    P.lossAcc = (float*)(ws + 4886528);
    P.out = (float*)d_out;

    // Replicate PHI_IDX with numpy-linspace double semantics (no FP contraction)
    volatile double a   = 1.0/3.0/4.0;
    volatile double bb  = 1.0 - a;
    volatile double stp = (bb - a) / 3.0;
    double ticks[4];
    for (int i = 0; i < 4; ++i) { volatile double m = (double)i * stp; ticks[i] = m + a; }
    ticks[3] = bb;
    for (int si = 0; si < 10; ++si) {
        volatile double x = (double)si / 9.0;
        int bidx = 0; double bd = fabs(ticks[0] - x);
        for (int k = 1; k < 4; ++k) {
            double d = fabs(ticks[k] - x);
            if (d < bd) { bd = d; bidx = k; }
        }
        P.phi[si] = bidx;
    }

    k_init<<<128, 256, 0, stream>>>(P.emb, (char*)ws, P.lossAcc, P.ctr);

    void* args[] = { (void*)&P };
    hipLaunchCooperativeKernel((const void*)k_mega, dim3(256), dim3(512),
                               args, 0, stream);

    k_final<<<1, 64, 0, stream>>>(P.lossAcc, P.out);
}

// Round 13
// 763.509 us; speedup vs baseline: 2.8827x; 1.1376x over previous
//
#include <hip/hip_runtime.h>
#include <math.h>
#include <stdint.h>

#define B_ 32
#define C_ 32
#define H_ 16
#define V_ 8192
#define NELEM (B_*C_*H_*H_)   // 262144
#define TBYTES 6208           // per 16-code tile: 3*2048 A-frag planes + 64 e2sq
#define ZB_PLANE 65536        // u64 per zb plane
#define FR_STR 5              // frL/fhL row stride (floats)

typedef short bf16x8 __attribute__((ext_vector_type(8)));
typedef unsigned short u16x8 __attribute__((ext_vector_type(8)));
typedef float f32x4 __attribute__((ext_vector_type(4)));
typedef unsigned long long ull;

__device__ __forceinline__ unsigned int fkey(float f) {
    unsigned int u = __float_as_uint(f);
    return (u & 0x80000000u) ? ~u : (u | 0x80000000u);
}
__device__ __forceinline__ unsigned short f2bf(float x) {
    unsigned int u = __float_as_uint(x);
    unsigned int r = u + 0x7fffu + ((u >> 16) & 1u);
    return (unsigned short)(r >> 16);
}
__device__ __forceinline__ float bf2f(unsigned short h) {
    return __uint_as_float(((unsigned int)h) << 16);
}

// coherent-point (agent-scope) atomic access; relaxed = no L2 flush
__device__ __forceinline__ void ast(ull* p, ull v) {
    __hip_atomic_store(p, v, __ATOMIC_RELAXED, __HIP_MEMORY_SCOPE_AGENT);
}
__device__ __forceinline__ ull ald(const ull* p) {
    return __hip_atomic_load((ull*)p, __ATOMIC_RELAXED, __HIP_MEMORY_SCOPE_AGENT);
}

// build E-fragment blob (A-frag order, -2E bf16x3 + e2sq); zero ctr/lossAcc
__global__ void __launch_bounds__(256) k_init(
    const float* __restrict__ emb, char* __restrict__ blob,
    float* __restrict__ lossAcc, unsigned int* __restrict__ ctr)
{
    int i = blockIdx.x*256 + threadIdx.x;   // 32768 = 512 tiles * 64
    int t = i >> 6, l = i & 63;
    int row = t*16 + (l & 15);
    int k0 = (l >> 4) * 8;
    const float* er = emb + row*C_ + k0;
    u16x8 h0, h1, h2;
    #pragma unroll
    for (int j = 0; j < 8; ++j) {
        float x = -2.f * er[j];
        unsigned short b0 = f2bf(x);  float r1 = x - bf2f(b0);
        unsigned short b1 = f2bf(r1); float r2 = r1 - bf2f(b1);
        unsigned short b2 = f2bf(r2);
        h0[j] = b0; h1[j] = b1; h2[j] = b2;
    }
    char* tb = blob + (size_t)t*TBYTES;
    *(u16x8*)(tb +        l*16) = h0;
    *(u16x8*)(tb + 2048 + l*16) = h1;
    *(u16x8*)(tb + 4096 + l*16) = h2;
    if ((l >> 4) == 0) {
        const float4* e4 = (const float4*)(emb + row*C_);
        float s = 0.f;
        #pragma unroll
        for (int cc = 0; cc < 8; ++cc) {
            float4 ev = e4[cc];
            s += ev.x*ev.x + ev.y*ev.y + ev.z*ev.z + ev.w*ev.w;
        }
        *(float*)(tb + 6144 + (l & 15)*4) = s;
    }
    if (i < 1024) ctr[i] = 0;
    if (i == 0) lossAcc[0] = 0.f;
}

__device__ __forceinline__ void qstep(
    const bf16x8 a0, const bf16x8 a1, const bf16x8 a2, const f32x4 e2v,
    const bf16x8* Bf, int cbase, float& dmin, int& imin)
{
    f32x4 acc = e2v;
    acc = __builtin_amdgcn_mfma_f32_16x16x32_bf16(a0, Bf[0], acc, 0, 0, 0);
    acc = __builtin_amdgcn_mfma_f32_16x16x32_bf16(a1, Bf[0], acc, 0, 0, 0);
    acc = __builtin_amdgcn_mfma_f32_16x16x32_bf16(a0, Bf[1], acc, 0, 0, 0);
    acc = __builtin_amdgcn_mfma_f32_16x16x32_bf16(a2, Bf[0], acc, 0, 0, 0);
    acc = __builtin_amdgcn_mfma_f32_16x16x32_bf16(a1, Bf[1], acc, 0, 0, 0);
    acc = __builtin_amdgcn_mfma_f32_16x16x32_bf16(a0, Bf[2], acc, 0, 0, 0);
    float mt = fminf(fminf(acc.x, acc.y), fminf(acc.z, acc.w));
    if (mt < dmin) {
        dmin = mt;
        imin = cbase + ((acc.x==mt) ? 0 : (acc.y==mt) ? 1 : (acc.z==mt) ? 2 : 3);
    }
}

__device__ __forceinline__ void cubic_taps(int i, int pn, float* wt, int* col) {
    double src = ((double)i + 0.5) * ((double)pn / 16.0) - 0.5;
    double fl = floor(src);
    const double A = -0.75;
    #pragma unroll
    for (int k = 0; k < 4; ++k) {
        double j = fl - 1.0 + (double)k;
        double d = fabs(src - j);
        double w;
        if (d <= 1.0)      w = ((A+2.0)*d - (A+3.0))*d*d + 1.0;
        else if (d < 2.0)  w = ((A*d - 5.0*A)*d + 8.0*A)*d - 4.0*A;
        else               w = 0.0;
        wt[k] = (float)w;
        int jj = (int)j;
        col[k] = jj < 0 ? 0 : (jj > pn-1 ? pn-1 : jj);
    }
}

// per-image 8-block barrier, RELAXED atomics (no L2 flush).
// __syncthreads drains each thread's vmcnt => prior atomic stores complete.
__device__ __forceinline__ void img_barrier(unsigned int* c) {
    __syncthreads();
    if (threadIdx.x == 0) {
        __hip_atomic_fetch_add(c, 1u, __ATOMIC_RELAXED, __HIP_MEMORY_SCOPE_AGENT);
        while (__hip_atomic_load(c, __ATOMIC_RELAXED, __HIP_MEMORY_SCOPE_AGENT) < 8u)
            __builtin_amdgcn_s_sleep(2);
    }
    __builtin_amdgcn_sched_barrier(0);
    __syncthreads();
}

// pool this block's 4 channels of frL -> zb (bf16x3 planes, packed u64 atomics)
__device__ void pool_to_zb(const float* frL, ull* zb, int bi, int pn2, int j, int tid)
{
    int pp2 = pn2*pn2;
    for (int cell = tid; cell < pp2; cell += 512) {
        int h2 = cell / pn2, w2 = cell - h2*pn2;
        int hs = (h2*H_)/pn2,  he = ((h2+1)*H_ + pn2-1)/pn2;
        int ws = (w2*H_)/pn2,  we = ((w2+1)*H_ + pn2-1)/pn2;
        float inv = (1.f/(float)(he-hs)) * (1.f/(float)(we-ws));
        ull p0 = 0, p1 = 0, p2 = 0;
        #pragma unroll
        for (int k = 0; k < 4; ++k) {
            float s = 0.f;
            for (int hh = hs; hh < he; ++hh)
                for (int ww = ws; ww < we; ++ww)
                    s += frL[(hh*H_+ww)*FR_STR + k];
            float x = s * inv;
            unsigned short b0 = f2bf(x);  float r1 = x - bf2f(b0);
            unsigned short b1 = f2bf(r1); float r2 = r1 - bf2f(b1);
            unsigned short b2 = f2bf(r2);
            p0 |= (ull)b0 << (16*k);
            p1 |= (ull)b1 << (16*k);
            p2 |= (ull)b2 << (16*k);
        }
        size_t g = (size_t)(bi*pp2 + cell)*8 + j;
        ast(zb + g, p0);
        ast(zb + ZB_PLANE + g, p1);
        ast(zb + 2*ZB_PLANE + g, p2);
    }
}

struct MegaP {
    const float *f, *emb, *cw, *cb;
    const char* blob;
    ull* zb;
    ull* best0; ull* best1;
    unsigned int* ctr;
    float* lossAcc; float* out;
    int phi[10];
};

// 256 blocks x 512 thr; bi = blk&31 (siblings same XCD under %8 rr), j = blk>>5.
// Shard owns V-slice j (64 code tiles) + channels 4j..4j+3 in LDS all scales.
__global__ void __launch_bounds__(512, 2) k_mega(MegaP P)
{
    __shared__ float huL[256*33];      // full h_up (33.8 KB)
    __shared__ float frL[256*FR_STR];  // f_rest shard
    __shared__ float fhL[256*FR_STR];  // f_hat shard
    __shared__ ull   bestS[256];
    __shared__ float wtT[64];
    __shared__ int   colT[64];
    __shared__ float red[4];

    const int tid = threadIdx.x;
    const int bi = blockIdx.x & 31;
    const int j  = blockIdx.x >> 5;
    const int co0 = j*4;
    const int lane = tid & 63, wid = tid >> 6;
    const int qr = lane & 15, kq = lane >> 4;
    const float* fimg = P.f + (size_t)bi*8192;

    // prologue
    for (int it = tid; it < 1024; it += 512) {
        int k = it >> 8, px = it & 255;
        frL[px*FR_STR + k] = fimg[(co0+k)*256 + px];
        fhL[px*FR_STR + k] = 0.f;
    }
    for (int it = tid; it < 256; it += 512) ast(P.best0 + bi*256 + it, ~0ull);
    __syncthreads();
    pool_to_zb(frL, P.zb, bi, 1, j, tid);
    img_barrier(&P.ctr[bi*32 + 0]);

    static const int pns[10] = {1,2,3,4,5,6,8,10,13,16};

    for (int si = 0; si < 10; ++si) {
        const int pn = pns[si], pp = pn*pn;
        const int qt = (pp + 15) >> 4;
        const int npass = (qt > 8) ? 2 : 1;
        ull* bcur  = (si & 1) ? P.best1 : P.best0;
        ull* bnext = (si & 1) ? P.best0 : P.best1;

        // ---- VQ: shard's 64 code tiles (8/wave), 8 qtiles in regs per pass ----
        for (int p = 0; p < npass; ++p) {
            const int qbase = p*8;
            bf16x8 Bq[8][3];
            int vv[8];
            #pragma unroll
            for (int J = 0; J < 8; ++J) {
                int row = (qbase + J)*16 + qr;
                vv[J] = (row < pp);
                size_t g = (size_t)(bi*pp + (vv[J] ? row : 0))*8 + 2*kq;
                union { ull u[2]; bf16x8 v; } u0, u1, u2;
                u0.u[0] = ald(P.zb + g);
                u0.u[1] = ald(P.zb + g + 1);
                u1.u[0] = ald(P.zb + ZB_PLANE + g);
                u1.u[1] = ald(P.zb + ZB_PLANE + g + 1);
                u2.u[0] = ald(P.zb + 2*ZB_PLANE + g);
                u2.u[1] = ald(P.zb + 2*ZB_PLANE + g + 1);
                Bq[J][0] = u0.v; Bq[J][1] = u1.v; Bq[J][2] = u2.v;
            }
            float dmin[8]; int imin[8];
            #pragma unroll
            for (int J = 0; J < 8; ++J) { dmin[J] = __builtin_inff(); imin[J] = 0; }

            const int t0 = j*64 + wid*8;
            const char* tb = P.blob + (size_t)t0*TBYTES;
            bf16x8 Xa0, Xa1, Xa2; f32x4 Xe;
            bf16x8 Ya0, Ya1, Ya2; f32x4 Ye;
            Xa0 = *(const bf16x8*)(tb +        lane*16);
            Xa1 = *(const bf16x8*)(tb + 2048 + lane*16);
            Xa2 = *(const bf16x8*)(tb + 4096 + lane*16);
            Xe  = *(const f32x4*)(tb + 6144 + kq*16);

            for (int tt = 0; tt < 8; tt += 2) {
                const char* nb = tb + TBYTES;
                Ya0 = *(const bf16x8*)(nb +        lane*16);
                Ya1 = *(const bf16x8*)(nb + 2048 + lane*16);
                Ya2 = *(const bf16x8*)(nb + 4096 + lane*16);
                Ye  = *(const f32x4*)(nb + 6144 + kq*16);
                {
                    int cbase = (t0 + tt)*16 + kq*4;
                    #pragma unroll
                    for (int J = 0; J < 8; ++J)
                        qstep(Xa0, Xa1, Xa2, Xe, Bq[J], cbase, dmin[J], imin[J]);
                }
                const char* nb2 = (tt + 2 < 8) ? tb + 2*TBYTES : tb;
                Xa0 = *(const bf16x8*)(nb2 +        lane*16);
                Xa1 = *(const bf16x8*)(nb2 + 2048 + lane*16);
                Xa2 = *(const bf16x8*)(nb2 + 4096 + lane*16);
                Xe  = *(const f32x4*)(nb2 + 6144 + kq*16);
                {
                    int cbase = (t0 + tt + 1)*16 + kq*4;
                    #pragma unroll
                    for (int J = 0; J < 8; ++J)
                        qstep(Ya0, Ya1, Ya2, Ye, Bq[J], cbase, dmin[J], imin[J]);
                }
                tb += 2*TBYTES;
            }
            #pragma unroll
            for (int J = 0; J < 8; ++J) {
                ull key = ((ull)fkey(dmin[J]) << 32) | (unsigned int)imin[J];
                ull o1 = __shfl_xor(key, 16); key = o1 < key ? o1 : key;
                ull o2 = __shfl_xor(key, 32); key = o2 < key ? o2 : key;
                if (kq == 0 && vv[J])
                    atomicMin(&bcur[bi*256 + (qbase + J)*16 + qr], key);
            }
        }
        img_barrier(&P.ctr[bi*32 + 1 + 2*si]);

        // stage best + taps
        for (int it = tid; it < pp; it += 512) bestS[it] = ald(bcur + bi*256 + it);
        if (tid < 16) cubic_taps(tid, pn, &wtT[tid*4], &colT[tid*4]);
        __syncthreads();

        // ---- UP: full h_up (all 32 channels) into LDS ----
        for (int it = tid; it < 8192; it += 512) {
            int c = it & 31, px = it >> 5;
            int h = px >> 4, w2 = px & 15;
            float acc = 0.f;
            #pragma unroll
            for (int ii = 0; ii < 4; ++ii) {
                float whv = wtT[h*4+ii];
                if (whv == 0.f) continue;
                int th = colT[h*4+ii];
                #pragma unroll
                for (int jj = 0; jj < 4; ++jj) {
                    float wt = whv * wtT[w2*4+jj];
                    if (wt == 0.f) continue;
                    unsigned int idx =
                        (unsigned int)(bestS[th*pn + colT[w2*4+jj]] & 0xffffffffull);
                    acc = fmaf(wt, P.emb[(size_t)idx*C_ + c], acc);
                }
            }
            huL[px*33 + c] = acc;
        }
        __syncthreads();

        // ---- CONV (256 threads, 4 co each) + Phi + updates + loss ----
        if (tid < 256) {
            int px = tid;
            int h = px >> 4, w2 = px & 15;
            const float* cwp = P.cw + (size_t)P.phi[si]*9216;
            const float* cbp = P.cb + (size_t)P.phi[si]*C_;
            float o4[4];
            #pragma unroll
            for (int k = 0; k < 4; ++k) o4[k] = cbp[co0+k];
            for (int ci = 0; ci < 32; ++ci) {
                float hv[9];
                #pragma unroll
                for (int dh = 0; dh < 3; ++dh) {
                    int hh = h + dh - 1;
                    #pragma unroll
                    for (int dw = 0; dw < 3; ++dw) {
                        int ww = w2 + dw - 1;
                        bool ok = (hh >= 0) & (hh < 16) & (ww >= 0) & (ww < 16);
                        int npx = ((hh & 15) << 4) | (ww & 15);
                        hv[dh*3+dw] = ok ? huL[npx*33 + ci] : 0.f;
                    }
                }
                #pragma unroll
                for (int k = 0; k < 4; ++k) {
                    const float* wr = cwp + (size_t)((co0+k)*C_ + ci)*9;
                    float s = 0.f;
                    #pragma unroll
                    for (int t = 0; t < 9; ++t) s = fmaf(hv[t], wr[t], s);
                    o4[k] += s;
                }
            }
            float sq = 0.f;
            #pragma unroll
            for (int k = 0; k < 4; ++k) {
                int co = co0 + k;
                float hv0 = huL[px*33 + co];
                float outv = 0.5f*hv0 + 0.5f*o4[k];
                float fh = fhL[px*FR_STR + k] + outv;
                fhL[px*FR_STR + k] = fh;
                frL[px*FR_STR + k] -= outv;
                float df = fh - fimg[co*256 + px];
                sq = fmaf(df, df, sq);
            }
            #pragma unroll
            for (int o2 = 32; o2 > 0; o2 >>= 1) sq += __shfl_down(sq, o2, 64);
            if (lane == 0) red[wid] = sq;
        }
        __syncthreads();
        if (tid == 0) atomicAdd(P.lossAcc, (red[0]+red[1])+(red[2]+red[3]));

        if (si < 9) {
            pool_to_zb(frL, P.zb, bi, pns[si+1], j, tid);
            for (int it = tid; it < 256; it += 512)
                ast(bnext + bi*256 + it, ~0ull);
            img_barrier(&P.ctr[bi*32 + 2 + 2*si]);
        }
    }

    // epilogue: write this shard's channels of f_hat
    for (int it = tid; it < 1024; it += 512) {
        int k = it >> 8, px = it & 255;
        P.out[(size_t)bi*8192 + (co0+k)*256 + px] = fhL[px*FR_STR + k];
    }
}

__global__ void k_final(const float* __restrict__ lossAcc, float* __restrict__ out)
{
    if (blockIdx.x == 0 && threadIdx.x == 0)
        out[NELEM] = lossAcc[0] * 1.25f / ((float)NELEM * 10.f);
}

extern "C" void kernel_launch(void* const* d_in, const int* in_sizes, int n_in,
                              void* d_out, int out_size, void* d_ws, size_t ws_size,
                              hipStream_t stream)
{
    char* ws = (char*)d_ws;
    MegaP P;
    P.f   = (const float*)d_in[0];
    P.emb = (const float*)d_in[1];
    P.cw  = (const float*)d_in[2];
    P.cb  = (const float*)d_in[3];
    P.blob = ws;                                            // 3,178,496 B
    P.zb   = (ull*)(ws + 3178496);                          // 1,572,864 B
    P.best0 = (ull*)(ws + 4751360);                         // 65,536 B
    P.best1 = (ull*)(ws + 4816896);                         // 65,536 B
    P.ctr   = (unsigned int*)(ws + 4882432);                // 4,096 B
    P.lossAcc = (float*)(ws + 4886528);
    P.out = (float*)d_out;

    // Replicate PHI_IDX with numpy-linspace double semantics (no FP contraction)
    volatile double a   = 1.0/3.0/4.0;
    volatile double bb  = 1.0 - a;
    volatile double stp = (bb - a) / 3.0;
    double ticks[4];
    for (int i = 0; i < 4; ++i) { volatile double m = (double)i * stp; ticks[i] = m + a; }
    ticks[3] = bb;
    for (int si = 0; si < 10; ++si) {
        volatile double x = (double)si / 9.0;
        int bidx = 0; double bd = fabs(ticks[0] - x);
        for (int k = 1; k < 4; ++k) {
            double d = fabs(ticks[k] - x);
            if (d < bd) { bd = d; bidx = k; }
        }
        P.phi[si] = bidx;
    }

    k_init<<<128, 256, 0, stream>>>(P.emb, (char*)ws, P.lossAcc, P.ctr);

    void* args[] = { (void*)&P };
    hipLaunchCooperativeKernel((const void*)k_mega, dim3(256), dim3(512),
                               args, 0, stream);

    k_final<<<1, 64, 0, stream>>>(P.lossAcc, P.out);
}

// Round 14
// 677.366 us; speedup vs baseline: 3.2493x; 1.1272x over previous
//
#include <hip/hip_runtime.h>
#include <math.h>
#include <stdint.h>

#define B_ 32
#define C_ 32
#define H_ 16
#define V_ 8192
#define NELEM (B_*C_*H_*H_)   // 262144
#define TBYTES 6208           // per 16-code tile: 3*2048 A-frag planes + 64 e2sq
#define ZB_PLANE 65536        // u64 per zb plane
#define FR_STR 5              // frL/fhL row stride (floats)

typedef short bf16x8 __attribute__((ext_vector_type(8)));
typedef unsigned short u16x8 __attribute__((ext_vector_type(8)));
typedef float f32x4 __attribute__((ext_vector_type(4)));
typedef unsigned long long ull;

__device__ __forceinline__ unsigned int fkey(float f) {
    unsigned int u = __float_as_uint(f);
    return (u & 0x80000000u) ? ~u : (u | 0x80000000u);
}
__device__ __forceinline__ unsigned short f2bf(float x) {
    unsigned int u = __float_as_uint(x);
    unsigned int r = u + 0x7fffu + ((u >> 16) & 1u);
    return (unsigned short)(r >> 16);
}
__device__ __forceinline__ float bf2f(unsigned short h) {
    return __uint_as_float(((unsigned int)h) << 16);
}

// coherent-point (agent-scope) atomic access; relaxed = no L2 flush
__device__ __forceinline__ void ast(ull* p, ull v) {
    __hip_atomic_store(p, v, __ATOMIC_RELAXED, __HIP_MEMORY_SCOPE_AGENT);
}
__device__ __forceinline__ ull ald(const ull* p) {
    return __hip_atomic_load((ull*)p, __ATOMIC_RELAXED, __HIP_MEMORY_SCOPE_AGENT);
}

// build E-fragment blob (A-frag order, -2E bf16x3 + e2sq); zero ctr/lossAcc
__global__ void __launch_bounds__(256) k_init(
    const float* __restrict__ emb, char* __restrict__ blob,
    float* __restrict__ lossAcc, unsigned int* __restrict__ ctr)
{
    int i = blockIdx.x*256 + threadIdx.x;   // 32768 = 512 tiles * 64
    int t = i >> 6, l = i & 63;
    int row = t*16 + (l & 15);
    int k0 = (l >> 4) * 8;
    const float* er = emb + row*C_ + k0;
    u16x8 h0, h1, h2;
    #pragma unroll
    for (int j = 0; j < 8; ++j) {
        float x = -2.f * er[j];
        unsigned short b0 = f2bf(x);  float r1 = x - bf2f(b0);
        unsigned short b1 = f2bf(r1); float r2 = r1 - bf2f(b1);
        unsigned short b2 = f2bf(r2);
        h0[j] = b0; h1[j] = b1; h2[j] = b2;
    }
    char* tb = blob + (size_t)t*TBYTES;
    *(u16x8*)(tb +        l*16) = h0;
    *(u16x8*)(tb + 2048 + l*16) = h1;
    *(u16x8*)(tb + 4096 + l*16) = h2;
    if ((l >> 4) == 0) {
        const float4* e4 = (const float4*)(emb + row*C_);
        float s = 0.f;
        #pragma unroll
        for (int cc = 0; cc < 8; ++cc) {
            float4 ev = e4[cc];
            s += ev.x*ev.x + ev.y*ev.y + ev.z*ev.z + ev.w*ev.w;
        }
        *(float*)(tb + 6144 + (l & 15)*4) = s;
    }
    if (i < 1024) ctr[i] = 0;
    if (i == 0) lossAcc[0] = 0.f;
}

__device__ __forceinline__ void qstep(
    const bf16x8 a0, const bf16x8 a1, const bf16x8 a2, const f32x4 e2v,
    const bf16x8* Bf, int cbase, float& dmin, int& imin)
{
    f32x4 acc = e2v;
    acc = __builtin_amdgcn_mfma_f32_16x16x32_bf16(a0, Bf[0], acc, 0, 0, 0);
    acc = __builtin_amdgcn_mfma_f32_16x16x32_bf16(a1, Bf[0], acc, 0, 0, 0);
    acc = __builtin_amdgcn_mfma_f32_16x16x32_bf16(a0, Bf[1], acc, 0, 0, 0);
    acc = __builtin_amdgcn_mfma_f32_16x16x32_bf16(a2, Bf[0], acc, 0, 0, 0);
    acc = __builtin_amdgcn_mfma_f32_16x16x32_bf16(a1, Bf[1], acc, 0, 0, 0);
    acc = __builtin_amdgcn_mfma_f32_16x16x32_bf16(a0, Bf[2], acc, 0, 0, 0);
    float mt = fminf(fminf(acc.x, acc.y), fminf(acc.z, acc.w));
    if (mt < dmin) {
        dmin = mt;
        imin = cbase + ((acc.x==mt) ? 0 : (acc.y==mt) ? 1 : (acc.z==mt) ? 2 : 3);
    }
}

__device__ __forceinline__ void cubic_taps(int i, int pn, float* wt, int* col) {
    double src = ((double)i + 0.5) * ((double)pn / 16.0) - 0.5;
    double fl = floor(src);
    const double A = -0.75;
    #pragma unroll
    for (int k = 0; k < 4; ++k) {
        double j = fl - 1.0 + (double)k;
        double d = fabs(src - j);
        double w;
        if (d <= 1.0)      w = ((A+2.0)*d - (A+3.0))*d*d + 1.0;
        else if (d < 2.0)  w = ((A*d - 5.0*A)*d + 8.0*A)*d - 4.0*A;
        else               w = 0.0;
        wt[k] = (float)w;
        int jj = (int)j;
        col[k] = jj < 0 ? 0 : (jj > pn-1 ? pn-1 : jj);
    }
}

// per-image 8-block barrier, RELAXED atomics (no L2 flush).
// __syncthreads drains vmcnt => prior stores/atomics complete first.
__device__ __forceinline__ void img_barrier(unsigned int* c) {
    __syncthreads();
    if (threadIdx.x == 0) {
        __hip_atomic_fetch_add(c, 1u, __ATOMIC_RELAXED, __HIP_MEMORY_SCOPE_AGENT);
        while (__hip_atomic_load(c, __ATOMIC_RELAXED, __HIP_MEMORY_SCOPE_AGENT) < 8u)
            __builtin_amdgcn_s_sleep(1);
    }
    __builtin_amdgcn_sched_barrier(0);
    __syncthreads();
}

// pool this block's 4 channels of frL -> zb (bf16x3 planes, packed u64 atomics)
__device__ void pool_to_zb(const float* frL, ull* zb, int bi, int pn2, int j, int tid)
{
    int pp2 = pn2*pn2;
    for (int cell = tid; cell < pp2; cell += 512) {
        int h2 = cell / pn2, w2 = cell - h2*pn2;
        int hs = (h2*H_)/pn2,  he = ((h2+1)*H_ + pn2-1)/pn2;
        int ws = (w2*H_)/pn2,  we = ((w2+1)*H_ + pn2-1)/pn2;
        float inv = (1.f/(float)(he-hs)) * (1.f/(float)(we-ws));
        ull p0 = 0, p1 = 0, p2 = 0;
        #pragma unroll
        for (int k = 0; k < 4; ++k) {
            float s = 0.f;
            for (int hh = hs; hh < he; ++hh)
                for (int ww = ws; ww < we; ++ww)
                    s += frL[(hh*H_+ww)*FR_STR + k];
            float x = s * inv;
            unsigned short b0 = f2bf(x);  float r1 = x - bf2f(b0);
            unsigned short b1 = f2bf(r1); float r2 = r1 - bf2f(b1);
            unsigned short b2 = f2bf(r2);
            p0 |= (ull)b0 << (16*k);
            p1 |= (ull)b1 << (16*k);
            p2 |= (ull)b2 << (16*k);
        }
        size_t g = (size_t)(bi*pp2 + cell)*8 + j;
        ast(zb + g, p0);
        ast(zb + ZB_PLANE + g, p1);
        ast(zb + 2*ZB_PLANE + g, p2);
    }
}

struct MegaP {
    const float *f, *emb, *cw, *cb;
    const char* blob;
    ull* zb;
    ull* best0; ull* best1;
    unsigned int* ctr;
    float* lossAcc; float* out;
    int phi[10];
};

// 256 blocks x 512 thr; bi = blk&31, j = blk>>5.
// Shard owns V-slice j (64 code tiles) + channels 4j..4j+3 in LDS all scales.
__global__ void __launch_bounds__(512, 1) k_mega(MegaP P)
{
    __shared__ float huL[256*33];      // full h_up (33.8 KB)
    __shared__ float frL[256*FR_STR];  // f_rest shard
    __shared__ float fhL[256*FR_STR];  // f_hat shard
    __shared__ ull   bestS[256];
    __shared__ float wtT[64];
    __shared__ int   colT[64];
    __shared__ float red[8];

    const int tid = threadIdx.x;
    const int bi = blockIdx.x & 31;
    const int j  = blockIdx.x >> 5;
    const int co0 = j*4;
    const int lane = tid & 63, wid = tid >> 6;
    const int qr = lane & 15, kq = lane >> 4;
    const float* fimg = P.f + (size_t)bi*8192;

    // prologue
    for (int it = tid; it < 1024; it += 512) {
        int k = it >> 8, px = it & 255;
        frL[px*FR_STR + k] = fimg[(co0+k)*256 + px];
        fhL[px*FR_STR + k] = 0.f;
    }
    for (int it = tid; it < 256; it += 512) ast(P.best0 + bi*256 + it, ~0ull);
    __syncthreads();
    pool_to_zb(frL, P.zb, bi, 1, j, tid);
    img_barrier(&P.ctr[bi*32 + 0]);

    static const int pns[10] = {1,2,3,4,5,6,8,10,13,16};

    for (int si = 0; si < 10; ++si) {
        const int pn = pns[si], pp = pn*pn;
        const int qt = (pp + 15) >> 4;
        const int npass = (qt + 3) >> 2;
        ull* bcur  = (si & 1) ? P.best1 : P.best0;
        ull* bnext = (si & 1) ? P.best0 : P.best1;

        // ---- VQ: shard's 64 code tiles (8/wave), 4 qtile slots per pass ----
        for (int p = 0; p < npass; ++p) {
            const int qbase = p*4;
            const int jmax = qt - qbase;   // 1..4, wave-uniform
            bf16x8 B0[3], B1[3], B2[3], B3[3];
            int v0 = 0, v1 = 0, v2 = 0, v3 = 0;
            {
                int row; size_t g;
                union { ull u[2]; bf16x8 v; } u0, u1, u2;
                // slot 0 always valid (jmax >= 1)
                row = (qbase+0)*16 + qr; v0 = (row < pp);
                g = (size_t)(bi*pp + (v0 ? row : 0))*8 + 2*kq;
                u0.u[0] = ald(P.zb + g);              u0.u[1] = ald(P.zb + g + 1);
                u1.u[0] = ald(P.zb + ZB_PLANE + g);   u1.u[1] = ald(P.zb + ZB_PLANE + g + 1);
                u2.u[0] = ald(P.zb + 2*ZB_PLANE + g); u2.u[1] = ald(P.zb + 2*ZB_PLANE + g + 1);
                B0[0] = u0.v; B0[1] = u1.v; B0[2] = u2.v;
                if (jmax > 1) {
                    row = (qbase+1)*16 + qr; v1 = (row < pp);
                    g = (size_t)(bi*pp + (v1 ? row : 0))*8 + 2*kq;
                    u0.u[0] = ald(P.zb + g);              u0.u[1] = ald(P.zb + g + 1);
                    u1.u[0] = ald(P.zb + ZB_PLANE + g);   u1.u[1] = ald(P.zb + ZB_PLANE + g + 1);
                    u2.u[0] = ald(P.zb + 2*ZB_PLANE + g); u2.u[1] = ald(P.zb + 2*ZB_PLANE + g + 1);
                    B1[0] = u0.v; B1[1] = u1.v; B1[2] = u2.v;
                }
                if (jmax > 2) {
                    row = (qbase+2)*16 + qr; v2 = (row < pp);
                    g = (size_t)(bi*pp + (v2 ? row : 0))*8 + 2*kq;
                    u0.u[0] = ald(P.zb + g);              u0.u[1] = ald(P.zb + g + 1);
                    u1.u[0] = ald(P.zb + ZB_PLANE + g);   u1.u[1] = ald(P.zb + ZB_PLANE + g + 1);
                    u2.u[0] = ald(P.zb + 2*ZB_PLANE + g); u2.u[1] = ald(P.zb + 2*ZB_PLANE + g + 1);
                    B2[0] = u0.v; B2[1] = u1.v; B2[2] = u2.v;
                }
                if (jmax > 3) {
                    row = (qbase+3)*16 + qr; v3 = (row < pp);
                    g = (size_t)(bi*pp + (v3 ? row : 0))*8 + 2*kq;
                    u0.u[0] = ald(P.zb + g);              u0.u[1] = ald(P.zb + g + 1);
                    u1.u[0] = ald(P.zb + ZB_PLANE + g);   u1.u[1] = ald(P.zb + ZB_PLANE + g + 1);
                    u2.u[0] = ald(P.zb + 2*ZB_PLANE + g); u2.u[1] = ald(P.zb + 2*ZB_PLANE + g + 1);
                    B3[0] = u0.v; B3[1] = u1.v; B3[2] = u2.v;
                }
            }
            float d0 = __builtin_inff(), d1 = d0, d2 = d0, d3 = d0;
            int i0 = 0, i1 = 0, i2 = 0, i3 = 0;

            const int t0 = j*64 + wid*8;
            const char* tb = P.blob + (size_t)t0*TBYTES;
            bf16x8 Xa0, Xa1, Xa2; f32x4 Xe;
            bf16x8 Ya0, Ya1, Ya2; f32x4 Ye;
            Xa0 = *(const bf16x8*)(tb +        lane*16);
            Xa1 = *(const bf16x8*)(tb + 2048 + lane*16);
            Xa2 = *(const bf16x8*)(tb + 4096 + lane*16);
            Xe  = *(const f32x4*)(tb + 6144 + kq*16);

            for (int tt = 0; tt < 8; tt += 2) {
                const char* nb = tb + TBYTES;
                Ya0 = *(const bf16x8*)(nb +        lane*16);
                Ya1 = *(const bf16x8*)(nb + 2048 + lane*16);
                Ya2 = *(const bf16x8*)(nb + 4096 + lane*16);
                Ye  = *(const f32x4*)(nb + 6144 + kq*16);
                {
                    int cbase = (t0 + tt)*16 + kq*4;
                    qstep(Xa0, Xa1, Xa2, Xe, B0, cbase, d0, i0);
                    if (jmax > 1) qstep(Xa0, Xa1, Xa2, Xe, B1, cbase, d1, i1);
                    if (jmax > 2) qstep(Xa0, Xa1, Xa2, Xe, B2, cbase, d2, i2);
                    if (jmax > 3) qstep(Xa0, Xa1, Xa2, Xe, B3, cbase, d3, i3);
                }
                const char* nb2 = (tt + 2 < 8) ? tb + 2*TBYTES : tb;
                Xa0 = *(const bf16x8*)(nb2 +        lane*16);
                Xa1 = *(const bf16x8*)(nb2 + 2048 + lane*16);
                Xa2 = *(const bf16x8*)(nb2 + 4096 + lane*16);
                Xe  = *(const f32x4*)(nb2 + 6144 + kq*16);
                {
                    int cbase = (t0 + tt + 1)*16 + kq*4;
                    qstep(Ya0, Ya1, Ya2, Ye, B0, cbase, d0, i0);
                    if (jmax > 1) qstep(Ya0, Ya1, Ya2, Ye, B1, cbase, d1, i1);
                    if (jmax > 2) qstep(Ya0, Ya1, Ya2, Ye, B2, cbase, d2, i2);
                    if (jmax > 3) qstep(Ya0, Ya1, Ya2, Ye, B3, cbase, d3, i3);
                }
                tb += 2*TBYTES;
            }
            {
                ull key = ((ull)fkey(d0) << 32) | (unsigned int)i0;
                ull o1 = __shfl_xor(key, 16); key = o1 < key ? o1 : key;
                ull o2 = __shfl_xor(key, 32); key = o2 < key ? o2 : key;
                if (kq == 0 && v0) atomicMin(&bcur[bi*256 + (qbase+0)*16 + qr], key);
            }
            if (jmax > 1) {
                ull key = ((ull)fkey(d1) << 32) | (unsigned int)i1;
                ull o1 = __shfl_xor(key, 16); key = o1 < key ? o1 : key;
                ull o2 = __shfl_xor(key, 32); key = o2 < key ? o2 : key;
                if (kq == 0 && v1) atomicMin(&bcur[bi*256 + (qbase+1)*16 + qr], key);
            }
            if (jmax > 2) {
                ull key = ((ull)fkey(d2) << 32) | (unsigned int)i2;
                ull o1 = __shfl_xor(key, 16); key = o1 < key ? o1 : key;
                ull o2 = __shfl_xor(key, 32); key = o2 < key ? o2 : key;
                if (kq == 0 && v2) atomicMin(&bcur[bi*256 + (qbase+2)*16 + qr], key);
            }
            if (jmax > 3) {
                ull key = ((ull)fkey(d3) << 32) | (unsigned int)i3;
                ull o1 = __shfl_xor(key, 16); key = o1 < key ? o1 : key;
                ull o2 = __shfl_xor(key, 32); key = o2 < key ? o2 : key;
                if (kq == 0 && v3) atomicMin(&bcur[bi*256 + (qbase+3)*16 + qr], key);
            }
        }
        img_barrier(&P.ctr[bi*32 + 1 + 2*si]);

        // stage best + taps
        for (int it = tid; it < pp; it += 512) bestS[it] = ald(bcur + bi*256 + it);
        if (tid < 16) cubic_taps(tid, pn, &wtT[tid*4], &colT[tid*4]);
        __syncthreads();

        // ---- UP: full h_up (all 32 channels) into LDS ----
        for (int it = tid; it < 8192; it += 512) {
            int c = it & 31, px = it >> 5;
            int h = px >> 4, w2 = px & 15;
            float acc = 0.f;
            #pragma unroll
            for (int ii = 0; ii < 4; ++ii) {
                float whv = wtT[h*4+ii];
                if (whv == 0.f) continue;
                int th = colT[h*4+ii];
                #pragma unroll
                for (int jj = 0; jj < 4; ++jj) {
                    float wt = whv * wtT[w2*4+jj];
                    if (wt == 0.f) continue;
                    unsigned int idx =
                        (unsigned int)(bestS[th*pn + colT[w2*4+jj]] & 0xffffffffull);
                    acc = fmaf(wt, P.emb[(size_t)idx*C_ + c], acc);
                }
            }
            huL[px*33 + c] = acc;
        }
        __syncthreads();

        // ---- CONV: 512 threads, (px, 2 co) each + Phi + updates + loss ----
        {
            int px = tid & 255, half = tid >> 8;
            int h = px >> 4, w2 = px & 15;
            int cA = co0 + half*2;
            const float* cwp = P.cw + (size_t)P.phi[si]*9216;
            const float* cbp = P.cb + (size_t)P.phi[si]*C_;
            float o0 = cbp[cA], o1 = cbp[cA+1];
            for (int ci = 0; ci < 32; ++ci) {
                float hv[9];
                #pragma unroll
                for (int dh = 0; dh < 3; ++dh) {
                    int hh = h + dh - 1;
                    #pragma unroll
                    for (int dw = 0; dw < 3; ++dw) {
                        int ww = w2 + dw - 1;
                        bool ok = (hh >= 0) & (hh < 16) & (ww >= 0) & (ww < 16);
                        int npx = ((hh & 15) << 4) | (ww & 15);
                        hv[dh*3+dw] = ok ? huL[npx*33 + ci] : 0.f;
                    }
                }
                const float* w0 = cwp + (size_t)(cA*C_ + ci)*9;
                const float* w1 = w0 + 288;
                float s0 = 0.f, s1 = 0.f;
                #pragma unroll
                for (int t = 0; t < 9; ++t) {
                    s0 = fmaf(hv[t], w0[t], s0);
                    s1 = fmaf(hv[t], w1[t], s1);
                }
                o0 += s0; o1 += s1;
            }
            float sq = 0.f;
            {
                int co = cA, kk = half*2;
                float hv0 = huL[px*33 + co];
                float outv = 0.5f*hv0 + 0.5f*o0;
                float fh = fhL[px*FR_STR + kk] + outv;
                fhL[px*FR_STR + kk] = fh;
                frL[px*FR_STR + kk] -= outv;
                float df = fh - fimg[co*256 + px];
                sq = fmaf(df, df, sq);
            }
            {
                int co = cA+1, kk = half*2+1;
                float hv0 = huL[px*33 + co];
                float outv = 0.5f*hv0 + 0.5f*o1;
                float fh = fhL[px*FR_STR + kk] + outv;
                fhL[px*FR_STR + kk] = fh;
                frL[px*FR_STR + kk] -= outv;
                float df = fh - fimg[co*256 + px];
                sq = fmaf(df, df, sq);
            }
            #pragma unroll
            for (int o2 = 32; o2 > 0; o2 >>= 1) sq += __shfl_down(sq, o2, 64);
            if (lane == 0) red[wid] = sq;
        }
        __syncthreads();
        if (tid == 0) {
            float s = 0.f;
            #pragma unroll
            for (int r = 0; r < 8; ++r) s += red[r];
            atomicAdd(P.lossAcc, s);
        }

        if (si < 9) {
            pool_to_zb(frL, P.zb, bi, pns[si+1], j, tid);
            for (int it = tid; it < 256; it += 512)
                ast(bnext + bi*256 + it, ~0ull);
            img_barrier(&P.ctr[bi*32 + 2 + 2*si]);
        }
    }

    // epilogue: write this shard's channels of f_hat
    for (int it = tid; it < 1024; it += 512) {
        int k = it >> 8, px = it & 255;
        P.out[(size_t)bi*8192 + (co0+k)*256 + px] = fhL[px*FR_STR + k];
    }
}

__global__ void k_final(const float* __restrict__ lossAcc, float* __restrict__ out)
{
    if (blockIdx.x == 0 && threadIdx.x == 0)
        out[NELEM] = lossAcc[0] * 1.25f / ((float)NELEM * 10.f);
}

extern "C" void kernel_launch(void* const* d_in, const int* in_sizes, int n_in,
                              void* d_out, int out_size, void* d_ws, size_t ws_size,
                              hipStream_t stream)
{
    char* ws = (char*)d_ws;
    MegaP P;
    P.f   = (const float*)d_in[0];
    P.emb = (const float*)d_in[1];
    P.cw  = (const float*)d_in[2];
    P.cb  = (const float*)d_in[3];
    P.blob = ws;                                            // 3,178,496 B
    P.zb   = (ull*)(ws + 3178496);                          // 1,572,864 B
    P.best0 = (ull*)(ws + 4751360);                         // 65,536 B
    P.best1 = (ull*)(ws + 4816896);                         // 65,536 B
    P.ctr   = (unsigned int*)(ws + 4882432);                // 4,096 B
    P.lossAcc = (float*)(ws + 4886528);
    P.out = (float*)d_out;

    // Replicate PHI_IDX with numpy-linspace double semantics (no FP contraction)
    volatile double a   = 1.0/3.0/4.0;
    volatile double bb  = 1.0 - a;
    volatile double stp = (bb - a) / 3.0;
    double ticks[4];
    for (int i = 0; i < 4; ++i) { volatile double m = (double)i * stp; ticks[i] = m + a; }
    ticks[3] = bb;
    for (int si = 0; si < 10; ++si) {
        volatile double x = (double)si / 9.0;
        int bidx = 0; double bd = fabs(ticks[0] - x);
        for (int k = 1; k < 4; ++k) {
            double d = fabs(ticks[k] - x);
            if (d < bd) { bd = d; bidx = k; }
        }
        P.phi[si] = bidx;
    }

    k_init<<<128, 256, 0, stream>>>(P.emb, (char*)ws, P.lossAcc, P.ctr);

    void* args[] = { (void*)&P };
    hipLaunchCooperativeKernel((const void*)k_mega, dim3(256), dim3(512),
                               args, 0, stream);

    k_final<<<1, 64, 0, stream>>>(P.lossAcc, P.out);
}